// Round 2
// baseline (40.371 us; speedup 1.0000x reference)
//
#include <hip/hip_runtime.h>

// PIT loss: x,y [B=8, C=4, CH=2, T=262144] f32. D = CH*T = 524288.
// dists[b,i,j] = (sum(y[b,i]^2) + sum(x[b,j]^2) - 2*sum(x[b,j]*y[b,i])) / D
// total = sum_b min_p sum_i dists[b,i,perm[p][i]]; assignments[b] = argmin perm.

#define BATCH   8
#define CDIM    4
#define DLEN    (2 * 262144)        // 524288 scalars per (b, c)
#define F4_PER_C (DLEN / 4)         // 131072 float4 per channel
#define BPB     256                 // blocks per batch
#define TPB     256
#define NVAL    24                  // 4 sx + 4 sy + 16 cross

// itertools.permutations(range(4)) lexicographic order
__device__ __constant__ int PERMS[24][4] = {
    {0,1,2,3},{0,1,3,2},{0,2,1,3},{0,2,3,1},{0,3,1,2},{0,3,2,1},
    {1,0,2,3},{1,0,3,2},{1,2,0,3},{1,2,3,0},{1,3,0,2},{1,3,2,0},
    {2,0,1,3},{2,0,3,1},{2,1,0,3},{2,1,3,0},{2,3,0,1},{2,3,1,0},
    {3,0,1,2},{3,0,2,1},{3,1,0,2},{3,1,2,0},{3,2,0,1},{3,2,1,0}
};

__global__ __launch_bounds__(TPB, 4) void pit_reduce(const float* __restrict__ x,
                                                     const float* __restrict__ y,
                                                     float* __restrict__ ws) {
    const int b   = blockIdx.x / BPB;
    const int blk = blockIdx.x % BPB;
    const int tid = threadIdx.x;

    // f4_per_block = 131072/256 = 512; iters = 512/256 = 2 (fully unrolled)
    const int p0 = blk * (F4_PER_C / BPB) + tid;        // iteration 0 position
    const int p1 = p0 + TPB;                            // iteration 1 position

    const float4* __restrict__ xb = (const float4*)(x + (size_t)b * CDIM * DLEN);
    const float4* __restrict__ yb = (const float4*)(y + (size_t)b * CDIM * DLEN);

    // Issue all 16 loads up front: 16 KB in flight per wave.
    float4 xv0[4], yv0[4], xv1[4], yv1[4];
#pragma unroll
    for (int c = 0; c < 4; ++c) xv0[c] = xb[(size_t)c * F4_PER_C + p0];
#pragma unroll
    for (int c = 0; c < 4; ++c) yv0[c] = yb[(size_t)c * F4_PER_C + p0];
#pragma unroll
    for (int c = 0; c < 4; ++c) xv1[c] = xb[(size_t)c * F4_PER_C + p1];
#pragma unroll
    for (int c = 0; c < 4; ++c) yv1[c] = yb[(size_t)c * F4_PER_C + p1];

    float sx[4] = {0.f, 0.f, 0.f, 0.f};
    float sy[4] = {0.f, 0.f, 0.f, 0.f};
    float cr[4][4] = {};

#pragma unroll
    for (int c = 0; c < 4; ++c) {
        sx[c] += xv0[c].x * xv0[c].x + xv0[c].y * xv0[c].y +
                 xv0[c].z * xv0[c].z + xv0[c].w * xv0[c].w;
        sy[c] += yv0[c].x * yv0[c].x + yv0[c].y * yv0[c].y +
                 yv0[c].z * yv0[c].z + yv0[c].w * yv0[c].w;
    }
#pragma unroll
    for (int i = 0; i < 4; ++i)
#pragma unroll
        for (int j = 0; j < 4; ++j)
            cr[i][j] += yv0[i].x * xv0[j].x + yv0[i].y * xv0[j].y +
                        yv0[i].z * xv0[j].z + yv0[i].w * xv0[j].w;

#pragma unroll
    for (int c = 0; c < 4; ++c) {
        sx[c] += xv1[c].x * xv1[c].x + xv1[c].y * xv1[c].y +
                 xv1[c].z * xv1[c].z + xv1[c].w * xv1[c].w;
        sy[c] += yv1[c].x * yv1[c].x + yv1[c].y * yv1[c].y +
                 yv1[c].z * yv1[c].z + yv1[c].w * yv1[c].w;
    }
#pragma unroll
    for (int i = 0; i < 4; ++i)
#pragma unroll
        for (int j = 0; j < 4; ++j)
            cr[i][j] += yv1[i].x * xv1[j].x + yv1[i].y * xv1[j].y +
                        yv1[i].z * xv1[j].z + yv1[i].w * xv1[j].w;

    // pack 24 accumulators: [0..3]=sx, [4..7]=sy, [8..23]=cr[i][j]
    float v[NVAL];
#pragma unroll
    for (int c = 0; c < 4; ++c) { v[c] = sx[c]; v[4 + c] = sy[c]; }
#pragma unroll
    for (int i = 0; i < 4; ++i)
#pragma unroll
        for (int j = 0; j < 4; ++j) v[8 + i * 4 + j] = cr[i][j];

    // wave64 tree reduce (deterministic)
#pragma unroll
    for (int k = 0; k < NVAL; ++k) {
#pragma unroll
        for (int off = 32; off > 0; off >>= 1)
            v[k] += __shfl_down(v[k], off);
    }

    __shared__ float red[4][NVAL];
    const int wave = tid >> 6, lane = tid & 63;
    if (lane == 0) {
#pragma unroll
        for (int k = 0; k < NVAL; ++k) red[wave][k] = v[k];
    }
    __syncthreads();
    if (tid < NVAL) {
        float s = red[0][tid] + red[1][tid] + red[2][tid] + red[3][tid];
        ws[(size_t)(b * BPB + blk) * NVAL + tid] = s;
    }
}

__global__ __launch_bounds__(256) void pit_finalize(const float* __restrict__ ws,
                                                    float* __restrict__ out) {
    __shared__ double stage[BATCH][NVAL];   // summed partials
    __shared__ double dists[BATCH][4][4];
    __shared__ double mins[BATCH];
    const int tid = threadIdx.x;

    if (tid < BATCH * NVAL) {               // 192 threads
        const int b = tid / NVAL, k = tid % NVAL;
        // 4 independent chains to shorten the serial fp64-add dependency
        double s0 = 0.0, s1 = 0.0, s2 = 0.0, s3 = 0.0;
        for (int blk = 0; blk < BPB; blk += 4) {
            s0 += (double)ws[(size_t)(b * BPB + blk + 0) * NVAL + k];
            s1 += (double)ws[(size_t)(b * BPB + blk + 1) * NVAL + k];
            s2 += (double)ws[(size_t)(b * BPB + blk + 2) * NVAL + k];
            s3 += (double)ws[(size_t)(b * BPB + blk + 3) * NVAL + k];
        }
        stage[b][k] = (s0 + s1) + (s2 + s3);
    }
    __syncthreads();

    if (tid < BATCH * 16) {                 // 128 threads
        const int b = tid / 16, ij = tid % 16, i = ij / 4, j = ij % 4;
        dists[b][i][j] = (stage[b][4 + i] + stage[b][j]
                          - 2.0 * stage[b][8 + i * 4 + j]) / (double)DLEN;
    }
    __syncthreads();

    if (tid < BATCH) {
        const int b = tid;
        double best = 1e300;
        int bestp = 0;
        for (int p = 0; p < 24; ++p) {
            double c = 0.0;
#pragma unroll
            for (int i = 0; i < 4; ++i) c += dists[b][i][PERMS[p][i]];
            if (c < best) { best = c; bestp = p; }   // strict <  => first min (jnp.argmin)
        }
        mins[b] = best;
#pragma unroll
        for (int i = 0; i < 4; ++i)
            out[1 + b * 4 + i] = (float)PERMS[bestp][i];
    }
    __syncthreads();

    if (tid == 0) {
        double tot = 0.0;
        for (int b = 0; b < BATCH; ++b) tot += mins[b];
        out[0] = (float)tot;
    }
}

extern "C" void kernel_launch(void* const* d_in, const int* in_sizes, int n_in,
                              void* d_out, int out_size, void* d_ws, size_t ws_size,
                              hipStream_t stream) {
    const float* x = (const float*)d_in[0];
    const float* y = (const float*)d_in[1];
    float* out = (float*)d_out;
    float* ws  = (float*)d_ws;     // needs 8*256*24*4 = 196608 bytes

    pit_reduce<<<BATCH * BPB, TPB, 0, stream>>>(x, y, ws);
    pit_finalize<<<1, 256, 0, stream>>>(ws, out);
}